// Round 1
// baseline (3898.510 us; speedup 1.0000x reference)
//
#include <hip/hip_runtime.h>
#include <hip/hip_bf16.h>

#define C 32
#define LN_EPS 1e-5f

__global__ __launch_bounds__(256) void osp_point_kernel(
    const float* __restrict__ voxel_feats,   // [V, 32]
    const float* __restrict__ xyz,           // [N, 3]
    const float* __restrict__ W1,            // [3, 32]
    const float* __restrict__ b1,            // [32]
    const float* __restrict__ gamma,         // [32]
    const float* __restrict__ beta,          // [32]
    const float* __restrict__ W2,            // [32, 32]
    const float* __restrict__ b2,            // [32]
    const int*   __restrict__ p2v,           // [N]
    const int*   __restrict__ sp_ids,        // [N]
    float* __restrict__ acc_x,               // [S, 32]  (= d_out region 0)
    float* __restrict__ acc_xyz,             // [S, 3]   (= d_out region 1)
    float* __restrict__ counts,              // [S]      (in d_ws)
    int n_pts)
{
    int p = blockIdx.x * blockDim.x + threadIdx.x;
    if (p >= n_pts) return;

    float x0 = xyz[3 * p + 0];
    float x1 = xyz[3 * p + 1];
    float x2 = xyz[3 * p + 2];
    int v  = p2v[p];
    int sp = sp_ids[p];

    // ---- Linear(3,32): h = xyz @ W1 + b1  (W1 accesses are wave-uniform -> s_load)
    float h[C];
    #pragma unroll
    for (int c = 0; c < C; ++c) {
        h[c] = fmaf(x0, W1[c], fmaf(x1, W1[C + c], fmaf(x2, W1[2 * C + c], b1[c])));
    }

    // ---- LayerNorm(32) over registers (per-thread, no cross-lane)
    float s = 0.f, s2 = 0.f;
    #pragma unroll
    for (int c = 0; c < C; ++c) { s += h[c]; s2 += h[c] * h[c]; }
    float mu   = s * (1.0f / C);
    float var  = fmaf(-mu, mu, s2 * (1.0f / C));
    float rstd = rsqrtf(var + LN_EPS);

    // ---- affine + ReLU
    float r[C];
    #pragma unroll
    for (int c = 0; c < C; ++c) {
        float t = fmaf((h[c] - mu) * rstd, gamma[c], beta[c]);
        r[c] = fmaxf(t, 0.0f);
    }

    // ---- Linear(32,32): acc = r @ W2 + b2 (W2 wave-uniform -> scalar operand FMAs)
    float acc[C];
    #pragma unroll
    for (int c = 0; c < C; ++c) acc[c] = b2[c];
    #pragma unroll
    for (int k = 0; k < C; ++k) {
        float rk = r[k];
        #pragma unroll
        for (int c = 0; c < C; ++c) {
            acc[c] = fmaf(rk, W2[k * C + c], acc[c]);
        }
    }

    // ---- gather voxel feature (128 contiguous bytes per thread) + scatter-add
    const float* vf = voxel_feats + (size_t)v * C;
    float* dst = acc_x + (size_t)sp * C;
    #pragma unroll
    for (int c = 0; c < C; ++c) {
        atomicAdd(&dst[c], acc[c] + vf[c]);
    }
    float* dxyz = acc_xyz + (size_t)sp * 3;
    atomicAdd(&dxyz[0], x0);
    atomicAdd(&dxyz[1], x1);
    atomicAdd(&dxyz[2], x2);
    atomicAdd(&counts[sp], 1.0f);
}

__global__ __launch_bounds__(256) void osp_finalize_kernel(
    float* __restrict__ out, const float* __restrict__ counts, int S)
{
    int i = blockIdx.x * blockDim.x + threadIdx.x;
    int total = S * 35;
    if (i >= total) return;
    int sp;
    if (i < S * C) sp = i >> 5;            // x_sp region: [S,32]
    else           sp = (i - S * C) / 3;   // sp_xyz region: [S,3]
    float d = fmaxf(counts[sp], 1.0f);
    out[i] = out[i] * (1.0f / d);
}

extern "C" void kernel_launch(void* const* d_in, const int* in_sizes, int n_in,
                              void* d_out, int out_size, void* d_ws, size_t ws_size,
                              hipStream_t stream)
{
    const float* voxel_feats = (const float*)d_in[0];
    const float* xyz         = (const float*)d_in[1];
    const float* W1          = (const float*)d_in[2];
    const float* b1          = (const float*)d_in[3];
    const float* gamma       = (const float*)d_in[4];
    const float* beta        = (const float*)d_in[5];
    const float* W2          = (const float*)d_in[6];
    const float* b2          = (const float*)d_in[7];
    const int*   p2v         = (const int*)d_in[8];
    const int*   sp_ids      = (const int*)d_in[9];

    const int n_pts = in_sizes[8];          // p2v_map length = N_POINTS
    const int S     = out_size / 35;        // out = [S*32] ++ [S*3]

    float* acc_x   = (float*)d_out;
    float* acc_xyz = acc_x + (size_t)S * C;
    float* counts  = (float*)d_ws;

    // accumulators must start at zero (d_out / d_ws are poisoned each call)
    hipMemsetAsync(d_out, 0, (size_t)out_size * sizeof(float), stream);
    hipMemsetAsync(counts, 0, (size_t)S * sizeof(float), stream);

    int blk = 256;
    int grid = (n_pts + blk - 1) / blk;
    osp_point_kernel<<<grid, blk, 0, stream>>>(
        voxel_feats, xyz, W1, b1, gamma, beta, W2, b2,
        p2v, sp_ids, acc_x, acc_xyz, counts, n_pts);

    int total = S * 35;
    osp_finalize_kernel<<<(total + blk - 1) / blk, blk, 0, stream>>>(
        (float*)d_out, counts, S);
}

// Round 2
// 946.151 us; speedup vs baseline: 4.1204x; 4.1204x over previous
//
#include <hip/hip_runtime.h>
#include <hip/hip_bf16.h>

#define C 32
#define LN_EPS 1e-5f
#define P 8            // threads cooperating per superpoint in k4
#define SCAN_BLK 1024  // elements per scan block

// ---------- K1: histogram + within-segment rank (the ONLY global atomics) ----
__global__ __launch_bounds__(256) void k1_hist_rank(
    const int* __restrict__ sp_ids, int* __restrict__ count,
    int* __restrict__ rank, int n)
{
    int p = blockIdx.x * 256 + threadIdx.x;
    if (p >= n) return;
    int sp = sp_ids[p];
    rank[p] = atomicAdd(&count[sp], 1);
}

// ---------- K2a: per-block exclusive scan (1024 elems/block) -----------------
__global__ __launch_bounds__(SCAN_BLK) void k2a_scan_block(
    const int* __restrict__ count, int* __restrict__ off,
    int* __restrict__ bsum, int S)
{
    __shared__ int lds[SCAN_BLK];
    int t = threadIdx.x;
    int i = blockIdx.x * SCAN_BLK + t;
    int v = (i < S) ? count[i] : 0;
    lds[t] = v;
    __syncthreads();
    // Hillis-Steele inclusive scan
    for (int d = 1; d < SCAN_BLK; d <<= 1) {
        int add = (t >= d) ? lds[t - d] : 0;
        __syncthreads();
        lds[t] += add;
        __syncthreads();
    }
    int incl = lds[t];
    if (i < S) off[i] = incl - v;               // exclusive within block
    if (t == SCAN_BLK - 1) bsum[blockIdx.x] = incl;
}

// ---------- K2b: scan the block sums (<=64 blocks) in one wave ---------------
__global__ __launch_bounds__(64) void k2b_scan_bsums(int* __restrict__ bsum, int nb)
{
    int lane = threadIdx.x;
    int v = (lane < nb) ? bsum[lane] : 0;
    int own = v;
    for (int d = 1; d < 64; d <<= 1) {
        int u = __shfl_up(v, d, 64);
        if (lane >= d) v += u;
    }
    if (lane < nb) bsum[lane] = v - own;        // exclusive block prefix
}

// ---------- K2c: add block prefixes ------------------------------------------
__global__ __launch_bounds__(256) void k2c_add_prefix(
    int* __restrict__ off, const int* __restrict__ bsum, int S)
{
    int i = blockIdx.x * 256 + threadIdx.x;
    if (i >= S) return;
    off[i] += bsum[i / SCAN_BLK];
}

// ---------- K3: reorder point ids by superpoint (no atomics) -----------------
__global__ __launch_bounds__(256) void k3_reorder(
    const int* __restrict__ sp_ids, const int* __restrict__ rank,
    const int* __restrict__ off, int* __restrict__ order, int n)
{
    int p = blockIdx.x * 256 + threadIdx.x;
    if (p >= n) return;
    int sp = sp_ids[p];
    order[off[sp] + rank[p]] = p;
}

// ---------- K4: fused gather + pos-MLP + segmented mean (no atomics) ---------
__global__ __launch_bounds__(256) void k4_segment_mlp_mean(
    const float* __restrict__ voxel_feats,   // [V, 32]
    const float* __restrict__ xyz,           // [N, 3]
    const float* __restrict__ W1,            // [3, 32]
    const float* __restrict__ b1,            // [32]
    const float* __restrict__ gamma,         // [32]
    const float* __restrict__ beta,          // [32]
    const float* __restrict__ W2,            // [32, 32]
    const float* __restrict__ b2,            // [32]
    const int*   __restrict__ p2v,           // [N]
    const int*   __restrict__ order,         // [N] sorted point ids
    const int*   __restrict__ off,           // [S]
    const int*   __restrict__ count,         // [S]
    float* __restrict__ out_x,               // [S, 32]
    float* __restrict__ out_xyz,             // [S, 3]
    int S)
{
    int gt  = blockIdx.x * 256 + threadIdx.x;
    int sp  = gt >> 3;        // P = 8
    int sub = gt & 7;
    if (sp >= S) return;

    int n    = count[sp];
    int base = off[sp];

    float acc[C];
    #pragma unroll
    for (int c = 0; c < C; ++c) acc[c] = 0.f;
    float ax = 0.f, ay = 0.f, az = 0.f;
    int my_pts = 0;

    for (int i = sub; i < n; i += P) {
        int p = order[base + i];
        float x0 = xyz[3 * p + 0];
        float x1 = xyz[3 * p + 1];
        float x2 = xyz[3 * p + 2];
        int v = p2v[p];

        // Linear(3,32) -> h  (W1/b1 wave-uniform scalar loads)
        float h[C];
        #pragma unroll
        for (int c = 0; c < C; ++c)
            h[c] = fmaf(x0, W1[c], fmaf(x1, W1[C + c], fmaf(x2, W1[2 * C + c], b1[c])));

        // LayerNorm(32) in registers
        float s = 0.f, s2 = 0.f;
        #pragma unroll
        for (int c = 0; c < C; ++c) { s += h[c]; s2 += h[c] * h[c]; }
        float mu   = s * (1.0f / C);
        float var  = fmaf(-mu, mu, s2 * (1.0f / C));
        float rstd = rsqrtf(var + LN_EPS);

        // affine + ReLU (in place)
        #pragma unroll
        for (int c = 0; c < C; ++c)
            h[c] = fmaxf(fmaf((h[c] - mu) * rstd, gamma[c], beta[c]), 0.0f);

        // gather voxel feature row (128 contiguous B) straight into acc
        const float4* vf4 = (const float4*)(voxel_feats + (size_t)v * C);
        #pragma unroll
        for (int q = 0; q < 8; ++q) {
            float4 f = vf4[q];
            acc[4 * q + 0] += f.x;
            acc[4 * q + 1] += f.y;
            acc[4 * q + 2] += f.z;
            acc[4 * q + 3] += f.w;
        }

        // Linear(32,32) accumulated directly into acc (b2 folded in at end)
        #pragma unroll
        for (int k = 0; k < C; ++k) {
            float rk = h[k];
            #pragma unroll
            for (int c = 0; c < C; ++c)
                acc[c] = fmaf(rk, W2[k * C + c], acc[c]);
        }

        ax += x0; ay += x1; az += x2;
        ++my_pts;
    }

    // fold b2: each point contributes +b2[c]
    float fpts = (float)my_pts;
    #pragma unroll
    for (int c = 0; c < C; ++c) acc[c] = fmaf(fpts, b2[c], acc[c]);

    // butterfly reduce across the 8-lane group
    #pragma unroll
    for (int c = 0; c < C; ++c) {
        acc[c] += __shfl_xor(acc[c], 1);
        acc[c] += __shfl_xor(acc[c], 2);
        acc[c] += __shfl_xor(acc[c], 4);
    }
    ax += __shfl_xor(ax, 1); ax += __shfl_xor(ax, 2); ax += __shfl_xor(ax, 4);
    ay += __shfl_xor(ay, 1); ay += __shfl_xor(ay, 2); ay += __shfl_xor(ay, 4);
    az += __shfl_xor(az, 1); az += __shfl_xor(az, 2); az += __shfl_xor(az, 4);

    if (sub == 0) {
        float inv = 1.0f / fmaxf((float)n, 1.0f);
        float4* o4 = (float4*)(out_x + (size_t)sp * C);
        #pragma unroll
        for (int q = 0; q < 8; ++q) {
            float4 f;
            f.x = acc[4 * q + 0] * inv;
            f.y = acc[4 * q + 1] * inv;
            f.z = acc[4 * q + 2] * inv;
            f.w = acc[4 * q + 3] * inv;
            o4[q] = f;
        }
        out_xyz[3 * sp + 0] = ax * inv;
        out_xyz[3 * sp + 1] = ay * inv;
        out_xyz[3 * sp + 2] = az * inv;
    }
}

extern "C" void kernel_launch(void* const* d_in, const int* in_sizes, int n_in,
                              void* d_out, int out_size, void* d_ws, size_t ws_size,
                              hipStream_t stream)
{
    const float* voxel_feats = (const float*)d_in[0];
    const float* xyz         = (const float*)d_in[1];
    const float* W1          = (const float*)d_in[2];
    const float* b1          = (const float*)d_in[3];
    const float* gamma       = (const float*)d_in[4];
    const float* beta        = (const float*)d_in[5];
    const float* W2          = (const float*)d_in[6];
    const float* b2          = (const float*)d_in[7];
    const int*   p2v         = (const int*)d_in[8];
    const int*   sp_ids      = (const int*)d_in[9];

    const int n_pts = in_sizes[8];          // N_POINTS
    const int S     = out_size / 35;        // out = [S*32] ++ [S*3]

    float* out_x   = (float*)d_out;
    float* out_xyz = out_x + (size_t)S * C;

    // workspace layout (ints): count[S] | off[S] | bsum[64] | rank[N] | order[N]
    int* count = (int*)d_ws;
    int* off   = count + S;
    int* bsum  = off + S;
    int* rank  = bsum + 64;
    int* order = rank + n_pts;

    hipMemsetAsync(count, 0, (size_t)S * sizeof(int), stream);

    int blk = 256;
    int gpts = (n_pts + blk - 1) / blk;
    k1_hist_rank<<<gpts, blk, 0, stream>>>(sp_ids, count, rank, n_pts);

    int nb = (S + SCAN_BLK - 1) / SCAN_BLK;   // 49 for S=50000 (<=64 required)
    k2a_scan_block<<<nb, SCAN_BLK, 0, stream>>>(count, off, bsum, S);
    k2b_scan_bsums<<<1, 64, 0, stream>>>(bsum, nb);
    k2c_add_prefix<<<(S + blk - 1) / blk, blk, 0, stream>>>(off, bsum, S);

    k3_reorder<<<gpts, blk, 0, stream>>>(sp_ids, rank, off, order, n_pts);

    int n_thr = S * P;
    k4_segment_mlp_mean<<<(n_thr + blk - 1) / blk, blk, 0, stream>>>(
        voxel_feats, xyz, W1, b1, gamma, beta, W2, b2,
        p2v, order, off, count, out_x, out_xyz, S);
}

// Round 3
// 578.867 us; speedup vs baseline: 6.7347x; 1.6345x over previous
//
#include <hip/hip_runtime.h>
#include <hip/hip_bf16.h>

#define C 32
#define LN_EPS 1e-5f
#define P 8            // threads cooperating per superpoint in reduce kernels
#define SCAN_BLK 1024  // elements per scan block

// ---------- K1: histogram + within-segment rank (the ONLY global atomics) ----
__global__ __launch_bounds__(256) void k1_hist_rank(
    const int* __restrict__ sp_ids, int* __restrict__ count,
    int* __restrict__ rank, int n)
{
    int p = blockIdx.x * 256 + threadIdx.x;
    if (p >= n) return;
    int sp = sp_ids[p];
    rank[p] = atomicAdd(&count[sp], 1);
}

// ---------- K2a: per-block exclusive scan (1024 elems/block) -----------------
__global__ __launch_bounds__(SCAN_BLK) void k2a_scan_block(
    const int* __restrict__ count, int* __restrict__ off,
    int* __restrict__ bsum, int S)
{
    __shared__ int lds[SCAN_BLK];
    int t = threadIdx.x;
    int i = blockIdx.x * SCAN_BLK + t;
    int v = (i < S) ? count[i] : 0;
    lds[t] = v;
    __syncthreads();
    for (int d = 1; d < SCAN_BLK; d <<= 1) {
        int add = (t >= d) ? lds[t - d] : 0;
        __syncthreads();
        lds[t] += add;
        __syncthreads();
    }
    int incl = lds[t];
    if (i < S) off[i] = incl - v;
    if (t == SCAN_BLK - 1) bsum[blockIdx.x] = incl;
}

// ---------- K2b: scan the block sums (<=64 blocks) in one wave ---------------
__global__ __launch_bounds__(64) void k2b_scan_bsums(int* __restrict__ bsum, int nb)
{
    int lane = threadIdx.x;
    int v = (lane < nb) ? bsum[lane] : 0;
    int own = v;
    for (int d = 1; d < 64; d <<= 1) {
        int u = __shfl_up(v, d, 64);
        if (lane >= d) v += u;
    }
    if (lane < nb) bsum[lane] = v - own;
}

// ---------- K2c: add block prefixes ------------------------------------------
__global__ __launch_bounds__(256) void k2c_add_prefix(
    int* __restrict__ off, const int* __restrict__ bsum, int S)
{
    int i = blockIdx.x * 256 + threadIdx.x;
    if (i >= S) return;
    off[i] += bsum[i / SCAN_BLK];
}

// ---------- kA: streaming MLP, writes results into SORTED slots --------------
// thread = point (coalesced reads); output row j = off[sp]+rank[p]:
//   y_s[j]   : 32 bf16 (64 B)  = vf[p2v[p]] + posmlp(xyz[p])
//   xyz_s[j] : 3 fp32 (12 B)
__global__ __launch_bounds__(256) void kA_mlp_scatter(
    const float* __restrict__ voxel_feats,
    const float* __restrict__ xyz,
    const float* __restrict__ W1, const float* __restrict__ b1,
    const float* __restrict__ gamma, const float* __restrict__ beta,
    const float* __restrict__ W2, const float* __restrict__ b2,
    const int* __restrict__ p2v, const int* __restrict__ sp_ids,
    const int* __restrict__ rank, const int* __restrict__ off,
    unsigned int* __restrict__ y_s,     // [N, 16] packed bf16 pairs
    float* __restrict__ xyz_s,          // [N, 3]
    int n)
{
    int p = blockIdx.x * 256 + threadIdx.x;
    if (p >= n) return;

    float x0 = xyz[3 * p + 0];
    float x1 = xyz[3 * p + 1];
    float x2 = xyz[3 * p + 2];
    int v  = p2v[p];
    int sp = sp_ids[p];
    int j  = off[sp] + rank[p];

    // Linear(3,32)
    float h[C];
    #pragma unroll
    for (int c = 0; c < C; ++c)
        h[c] = fmaf(x0, W1[c], fmaf(x1, W1[C + c], fmaf(x2, W1[2 * C + c], b1[c])));

    // LayerNorm(32) in registers
    float s = 0.f, s2 = 0.f;
    #pragma unroll
    for (int c = 0; c < C; ++c) { s += h[c]; s2 += h[c] * h[c]; }
    float mu   = s * (1.0f / C);
    float var  = fmaf(-mu, mu, s2 * (1.0f / C));
    float rstd = rsqrtf(var + LN_EPS);

    // affine + ReLU
    #pragma unroll
    for (int c = 0; c < C; ++c)
        h[c] = fmaxf(fmaf((h[c] - mu) * rstd, gamma[c], beta[c]), 0.0f);

    // acc = b2 + vf + h @ W2
    float acc[C];
    const float4* vf4 = (const float4*)(voxel_feats + (size_t)v * C);
    #pragma unroll
    for (int q = 0; q < 8; ++q) {
        float4 f = vf4[q];
        acc[4 * q + 0] = b2[4 * q + 0] + f.x;
        acc[4 * q + 1] = b2[4 * q + 1] + f.y;
        acc[4 * q + 2] = b2[4 * q + 2] + f.z;
        acc[4 * q + 3] = b2[4 * q + 3] + f.w;
    }
    #pragma unroll
    for (int k = 0; k < C; ++k) {
        float rk = h[k];
        #pragma unroll
        for (int c = 0; c < C; ++c)
            acc[c] = fmaf(rk, W2[k * C + c], acc[c]);
    }

    // pack 32 fp32 -> 16 uint (bf16 pairs), one 64 B row
    unsigned int w[16];
    #pragma unroll
    for (int q = 0; q < 16; ++q) {
        __hip_bfloat162 bb = __float22bfloat162_rn(make_float2(acc[2 * q], acc[2 * q + 1]));
        w[q] = *reinterpret_cast<unsigned int*>(&bb);
    }
    uint4* dst = (uint4*)(y_s + (size_t)j * 16);
    dst[0] = make_uint4(w[0], w[1], w[2], w[3]);
    dst[1] = make_uint4(w[4], w[5], w[6], w[7]);
    dst[2] = make_uint4(w[8], w[9], w[10], w[11]);
    dst[3] = make_uint4(w[12], w[13], w[14], w[15]);

    float* xd = xyz_s + (size_t)j * 3;
    xd[0] = x0; xd[1] = x1; xd[2] = x2;
}

// ---------- kB: purely-sequential segmented mean -----------------------------
__global__ __launch_bounds__(256) void kB_reduce(
    const unsigned int* __restrict__ y_s,   // [N,16]
    const float* __restrict__ xyz_s,        // [N,3]
    const int* __restrict__ off, const int* __restrict__ count,
    float* __restrict__ out_x,              // [S,32]
    float* __restrict__ out_xyz,            // [S,3]
    int S)
{
    int gt  = blockIdx.x * 256 + threadIdx.x;
    int sp  = gt >> 3;
    int sub = gt & 7;
    if (sp >= S) return;

    int n    = count[sp];
    int base = off[sp];

    float acc[C];
    #pragma unroll
    for (int c = 0; c < C; ++c) acc[c] = 0.f;
    float ax = 0.f, ay = 0.f, az = 0.f;

    for (int i = sub; i < n; i += P) {
        const uint4* r4 = (const uint4*)(y_s + (size_t)(base + i) * 16);
        unsigned int w[16];
        *(uint4*)(w + 0)  = r4[0];
        *(uint4*)(w + 4)  = r4[1];
        *(uint4*)(w + 8)  = r4[2];
        *(uint4*)(w + 12) = r4[3];
        #pragma unroll
        for (int q = 0; q < 16; ++q) {
            acc[2 * q + 0] += __uint_as_float(w[q] << 16);
            acc[2 * q + 1] += __uint_as_float(w[q] & 0xFFFF0000u);
        }
        const float* xp = xyz_s + (size_t)(base + i) * 3;
        ax += xp[0]; ay += xp[1]; az += xp[2];
    }

    #pragma unroll
    for (int c = 0; c < C; ++c) {
        acc[c] += __shfl_xor(acc[c], 1);
        acc[c] += __shfl_xor(acc[c], 2);
        acc[c] += __shfl_xor(acc[c], 4);
    }
    ax += __shfl_xor(ax, 1); ax += __shfl_xor(ax, 2); ax += __shfl_xor(ax, 4);
    ay += __shfl_xor(ay, 1); ay += __shfl_xor(ay, 2); ay += __shfl_xor(ay, 4);
    az += __shfl_xor(az, 1); az += __shfl_xor(az, 2); az += __shfl_xor(az, 4);

    if (sub == 0) {
        float inv = 1.0f / fmaxf((float)n, 1.0f);
        float4* o4 = (float4*)(out_x + (size_t)sp * C);
        #pragma unroll
        for (int q = 0; q < 8; ++q) {
            float4 f;
            f.x = acc[4 * q + 0] * inv;
            f.y = acc[4 * q + 1] * inv;
            f.z = acc[4 * q + 2] * inv;
            f.w = acc[4 * q + 3] * inv;
            o4[q] = f;
        }
        out_xyz[3 * sp + 0] = ax * inv;
        out_xyz[3 * sp + 1] = ay * inv;
        out_xyz[3 * sp + 2] = az * inv;
    }
}

// ================= fallback path (R2 structure) if ws too small ==============
__global__ __launch_bounds__(256) void k3_reorder(
    const int* __restrict__ sp_ids, const int* __restrict__ rank,
    const int* __restrict__ off, int* __restrict__ order, int n)
{
    int p = blockIdx.x * 256 + threadIdx.x;
    if (p >= n) return;
    int sp = sp_ids[p];
    order[off[sp] + rank[p]] = p;
}

__global__ __launch_bounds__(256) void k4_segment_mlp_mean(
    const float* __restrict__ voxel_feats, const float* __restrict__ xyz,
    const float* __restrict__ W1, const float* __restrict__ b1,
    const float* __restrict__ gamma, const float* __restrict__ beta,
    const float* __restrict__ W2, const float* __restrict__ b2,
    const int* __restrict__ p2v, const int* __restrict__ order,
    const int* __restrict__ off, const int* __restrict__ count,
    float* __restrict__ out_x, float* __restrict__ out_xyz, int S)
{
    int gt  = blockIdx.x * 256 + threadIdx.x;
    int sp  = gt >> 3;
    int sub = gt & 7;
    if (sp >= S) return;

    int n    = count[sp];
    int base = off[sp];

    float acc[C];
    #pragma unroll
    for (int c = 0; c < C; ++c) acc[c] = 0.f;
    float ax = 0.f, ay = 0.f, az = 0.f;
    int my_pts = 0;

    for (int i = sub; i < n; i += P) {
        int p = order[base + i];
        float x0 = xyz[3 * p + 0];
        float x1 = xyz[3 * p + 1];
        float x2 = xyz[3 * p + 2];
        int v = p2v[p];

        float h[C];
        #pragma unroll
        for (int c = 0; c < C; ++c)
            h[c] = fmaf(x0, W1[c], fmaf(x1, W1[C + c], fmaf(x2, W1[2 * C + c], b1[c])));
        float s = 0.f, s2 = 0.f;
        #pragma unroll
        for (int c = 0; c < C; ++c) { s += h[c]; s2 += h[c] * h[c]; }
        float mu   = s * (1.0f / C);
        float var  = fmaf(-mu, mu, s2 * (1.0f / C));
        float rstd = rsqrtf(var + LN_EPS);
        #pragma unroll
        for (int c = 0; c < C; ++c)
            h[c] = fmaxf(fmaf((h[c] - mu) * rstd, gamma[c], beta[c]), 0.0f);

        const float4* vf4 = (const float4*)(voxel_feats + (size_t)v * C);
        #pragma unroll
        for (int q = 0; q < 8; ++q) {
            float4 f = vf4[q];
            acc[4 * q + 0] += f.x;
            acc[4 * q + 1] += f.y;
            acc[4 * q + 2] += f.z;
            acc[4 * q + 3] += f.w;
        }
        #pragma unroll
        for (int k = 0; k < C; ++k) {
            float rk = h[k];
            #pragma unroll
            for (int c = 0; c < C; ++c)
                acc[c] = fmaf(rk, W2[k * C + c], acc[c]);
        }
        ax += x0; ay += x1; az += x2;
        ++my_pts;
    }

    float fpts = (float)my_pts;
    #pragma unroll
    for (int c = 0; c < C; ++c) acc[c] = fmaf(fpts, b2[c], acc[c]);

    #pragma unroll
    for (int c = 0; c < C; ++c) {
        acc[c] += __shfl_xor(acc[c], 1);
        acc[c] += __shfl_xor(acc[c], 2);
        acc[c] += __shfl_xor(acc[c], 4);
    }
    ax += __shfl_xor(ax, 1); ax += __shfl_xor(ax, 2); ax += __shfl_xor(ax, 4);
    ay += __shfl_xor(ay, 1); ay += __shfl_xor(ay, 2); ay += __shfl_xor(ay, 4);
    az += __shfl_xor(az, 1); az += __shfl_xor(az, 2); az += __shfl_xor(az, 4);

    if (sub == 0) {
        float inv = 1.0f / fmaxf((float)n, 1.0f);
        float4* o4 = (float4*)(out_x + (size_t)sp * C);
        #pragma unroll
        for (int q = 0; q < 8; ++q) {
            float4 f;
            f.x = acc[4 * q + 0] * inv;
            f.y = acc[4 * q + 1] * inv;
            f.z = acc[4 * q + 2] * inv;
            f.w = acc[4 * q + 3] * inv;
            o4[q] = f;
        }
        out_xyz[3 * sp + 0] = ax * inv;
        out_xyz[3 * sp + 1] = ay * inv;
        out_xyz[3 * sp + 2] = az * inv;
    }
}

extern "C" void kernel_launch(void* const* d_in, const int* in_sizes, int n_in,
                              void* d_out, int out_size, void* d_ws, size_t ws_size,
                              hipStream_t stream)
{
    const float* voxel_feats = (const float*)d_in[0];
    const float* xyz         = (const float*)d_in[1];
    const float* W1          = (const float*)d_in[2];
    const float* b1          = (const float*)d_in[3];
    const float* gamma       = (const float*)d_in[4];
    const float* beta        = (const float*)d_in[5];
    const float* W2          = (const float*)d_in[6];
    const float* b2          = (const float*)d_in[7];
    const int*   p2v         = (const int*)d_in[8];
    const int*   sp_ids      = (const int*)d_in[9];

    const int n_pts = in_sizes[8];
    const int S     = out_size / 35;

    float* out_x   = (float*)d_out;
    float* out_xyz = out_x + (size_t)S * C;

    // common workspace head (ints): count[S] | off[S] | bsum[64] | rank[N]
    int* count = (int*)d_ws;
    int* off   = count + S;
    int* bsum  = off + S;
    int* rank  = bsum + 64;

    size_t head_bytes = ((size_t)2 * S + 64 + (size_t)n_pts) * sizeof(int);
    size_t needA = head_bytes + (size_t)n_pts * 64 + (size_t)n_pts * 12;

    int blk = 256;
    int gpts = (n_pts + blk - 1) / blk;
    int nb = (S + SCAN_BLK - 1) / SCAN_BLK;

    hipMemsetAsync(count, 0, (size_t)S * sizeof(int), stream);
    k1_hist_rank<<<gpts, blk, 0, stream>>>(sp_ids, count, rank, n_pts);
    k2a_scan_block<<<nb, SCAN_BLK, 0, stream>>>(count, off, bsum, S);
    k2b_scan_bsums<<<1, 64, 0, stream>>>(bsum, nb);
    k2c_add_prefix<<<(S + blk - 1) / blk, blk, 0, stream>>>(off, bsum, S);

    int n_thr = S * P;
    if (ws_size >= needA) {
        unsigned int* y_s = (unsigned int*)((char*)d_ws + head_bytes);
        float* xyz_s = (float*)((char*)d_ws + head_bytes + (size_t)n_pts * 64);

        kA_mlp_scatter<<<gpts, blk, 0, stream>>>(
            voxel_feats, xyz, W1, b1, gamma, beta, W2, b2,
            p2v, sp_ids, rank, off, y_s, xyz_s, n_pts);
        kB_reduce<<<(n_thr + blk - 1) / blk, blk, 0, stream>>>(
            y_s, xyz_s, off, count, out_x, out_xyz, S);
    } else {
        int* order = rank + n_pts;
        k3_reorder<<<gpts, blk, 0, stream>>>(sp_ids, rank, off, order, n_pts);
        k4_segment_mlp_mean<<<(n_thr + blk - 1) / blk, blk, 0, stream>>>(
            voxel_feats, xyz, W1, b1, gamma, beta, W2, b2,
            p2v, order, off, count, out_x, out_xyz, S);
    }
}